// Round 1
// baseline (189.002 us; speedup 1.0000x reference)
//
#include <hip/hip_runtime.h>

// Segment-mean pooling: x [N,128] fp32, batch [N] sorted int -> out [1024,128] fp32.
// batch sorted => each segment is a contiguous row range; block b owns segment b.

#define NSEG 1024
#define DDIM 128
#define D4   32   // DDIM / 4 floats per float4

__global__ __launch_bounds__(256) void seg_mean_kernel(
    const float4* __restrict__ x4,
    const int*    __restrict__ b32,
    float4*       __restrict__ out4,
    long N)
{
    const int seg = blockIdx.x;
    const int t   = threadIdx.x;

    // dtype sniff: if batch was stored as int64 (little-endian), then i32[odd]
    // indices are hi-words == 0 (all values < 1024). i32[N-1] (odd index) is a
    // hi-word under int64 => 0; under int32 it's the last sorted value (~1023).
    const bool is64 = (b32[N - 1] == 0);

    auto getb = [&](long i) -> int { return is64 ? b32[i << 1] : b32[i]; };

    // lower_bound(seg) -> start, lower_bound(seg+1) -> end
    long lo = 0, hi = N;
    while (lo < hi) {
        long mid = (lo + hi) >> 1;
        if (getb(mid) < seg) lo = mid + 1; else hi = mid;
    }
    const long start = lo;
    hi = N;
    while (lo < hi) {
        long mid = (lo + hi) >> 1;
        if (getb(mid) <= seg) lo = mid + 1; else hi = mid;
    }
    const long end = lo;
    const long cnt = end - start;

    const int c = t & 31;   // float4 column within row
    const int r = t >> 5;   // row offset within group of 8

    float4 a0 = {0.f,0.f,0.f,0.f}, a1 = {0.f,0.f,0.f,0.f};
    float4 a2 = {0.f,0.f,0.f,0.f}, a3 = {0.f,0.f,0.f,0.f};

    long row = start + r;
    // 4-deep unroll: 4 independent loads in flight per wave
    for (; row + 24 < end; row += 32) {
        float4 v0 = x4[(row      ) * D4 + c];
        float4 v1 = x4[(row +  8 ) * D4 + c];
        float4 v2 = x4[(row + 16 ) * D4 + c];
        float4 v3 = x4[(row + 24 ) * D4 + c];
        a0.x += v0.x; a0.y += v0.y; a0.z += v0.z; a0.w += v0.w;
        a1.x += v1.x; a1.y += v1.y; a1.z += v1.z; a1.w += v1.w;
        a2.x += v2.x; a2.y += v2.y; a2.z += v2.z; a2.w += v2.w;
        a3.x += v3.x; a3.y += v3.y; a3.z += v3.z; a3.w += v3.w;
    }
    for (; row < end; row += 8) {
        float4 v = x4[row * D4 + c];
        a0.x += v.x; a0.y += v.y; a0.z += v.z; a0.w += v.w;
    }
    a0.x += a1.x + a2.x + a3.x;
    a0.y += a1.y + a2.y + a3.y;
    a0.z += a1.z + a2.z + a3.z;
    a0.w += a1.w + a2.w + a3.w;

    __shared__ float4 red[256];
    red[t] = a0;
    __syncthreads();

    if (t < 32) {
        float4 s = red[t];
#pragma unroll
        for (int rr = 1; rr < 8; ++rr) {
            float4 v = red[t + 32 * rr];
            s.x += v.x; s.y += v.y; s.z += v.z; s.w += v.w;
        }
        const float inv = (cnt > 0) ? 1.0f / (float)cnt : 0.0f;
        s.x *= inv; s.y *= inv; s.z *= inv; s.w *= inv;
        out4[(long)seg * D4 + t] = s;
    }
}

extern "C" void kernel_launch(void* const* d_in, const int* in_sizes, int n_in,
                              void* d_out, int out_size, void* d_ws, size_t ws_size,
                              hipStream_t stream)
{
    const float4* x4  = (const float4*)d_in[0];
    const int*    b32 = (const int*)d_in[1];
    float4*       out = (float4*)d_out;
    const long N = (long)in_sizes[1];

    seg_mean_kernel<<<NSEG, 256, 0, stream>>>(x4, b32, out, N);
}